// Round 1
// baseline (1097.832 us; speedup 1.0000x reference)
//
#include <hip/hip_runtime.h>
#include <math.h>

typedef unsigned short ushort_t;
typedef unsigned int uint_t;

#define DIMC 128
#define GRIDG 8
#define NB 16
#define NL 4096

constexpr int TM = 32;                  // tokens per block (= one LCBAM channel group)
constexpr int CHI = 8;                  // input channels per K-chunk
constexpr int NCHK = DIMC / CHI;        // 16 chunks
constexpr int KCH = CHI * GRIDG * 2;    // 128 K per chunk
constexpr int KTOT = DIMC * GRIDG * 2;  // 2048

// ---------------- kernel 0: transpose coeffs -> [layer][k][o] bf16 ----------------
// k = (i*8+g)*2 + trig ; src fk_c[trig][o][i][g]
__global__ void prep_coef_k(const float* __restrict__ fk1,
                            const float* __restrict__ fk2,
                            ushort_t* __restrict__ coefT) {
  int idx = blockIdx.x * 256 + threadIdx.x;  // < 2*2048*128 = 524288
  int layer = idx >> 18;
  int r = idx & ((1 << 18) - 1);
  int o = r & 127;
  int k = r >> 7;
  int trig = k & 1;
  int ig = k >> 1;
  int g = ig & 7;
  int i = ig >> 3;
  const float* src = layer ? fk2 : fk1;
  float v = src[((trig * DIMC + o) * DIMC + i) * GRIDG + g];
  uint_t bits = __float_as_uint(v);            // round-to-nearest-even bf16
  uint_t lsb = (bits >> 16) & 1u;
  bits += 0x7fffu + lsb;
  coefT[idx] = (ushort_t)(bits >> 16);
}

// ---------------- kernel 1: LN1 -> FKAN1 -> ReLU -> LN2 -> FKAN2 + channel stats ----
__global__ __launch_bounds__(256) void fkan_main_k(
    const float* __restrict__ x,
    const float* __restrict__ n1g, const float* __restrict__ n1b,
    const float* __restrict__ fk1b,
    const float* __restrict__ n2g, const float* __restrict__ n2b,
    const float* __restrict__ fk2b,
    const ushort_t* __restrict__ coefT,
    float* __restrict__ out2,
    float* __restrict__ chanSum, float* __restrict__ chanMax) {

  __shared__ float xn[TM][DIMC];                       // 16 KB (x tile / normed)
  __shared__ float feat[KCH][TM];                      // 16 KB, [k][t] -> conflict-free reads
  __shared__ __align__(16) ushort_t clds[KCH][DIMC];   // 32 KB coeff chunk (bf16)
  float(*o1)[DIMC] = (float(*)[DIMC]) & clds[0][0];    // FKAN1 output reuses clds space

  const int tid = threadIdx.x;
  const int bid = blockIdx.x;
  const int b = bid >> 7;      // grid = 16*128, b-major
  const int c4 = bid & 127;
  const int lane = tid & 63;
  const int wid = tid >> 6;
  const int og = tid & 31;     // output group: o = og*4..og*4+3
  const int tg = tid >> 5;     // token group: t = tg*4..tg*4+3

  const size_t tileBase = ((size_t)(b * NL + c4 * TM)) * DIMC;

  {  // load 32x128 x-tile
    const float4* src = (const float4*)(x + tileBase);
    float4* dst = (float4*)&xn[0][0];
#pragma unroll
    for (int j = 0; j < 4; ++j) dst[tid + j * 256] = src[tid + j * 256];
  }
  __syncthreads();

  auto layernorm = [&](const float(*src)[DIMC], float(*dst)[DIMC],
                       const float* gg, const float* bb) {
    float g0 = gg[lane], g1 = gg[lane + 64];
    float be0 = bb[lane], be1 = bb[lane + 64];
#pragma unroll
    for (int j = 0; j < 8; ++j) {
      int t = wid * 8 + j;  // one wave owns token t
      float v0 = src[t][lane], v1 = src[t][lane + 64];
      float s = v0 + v1, q = v0 * v0 + v1 * v1;
#pragma unroll
      for (int m = 1; m < 64; m <<= 1) {
        s += __shfl_xor(s, m, 64);
        q += __shfl_xor(q, m, 64);
      }
      float mean = s * (1.0f / DIMC);
      float var = q * (1.0f / DIMC) - mean * mean;
      float rr = rsqrtf(var + 1e-5f);
      dst[t][lane] = (v0 - mean) * rr * g0 + be0;
      dst[t][lane + 64] = (v1 - mean) * rr * g1 + be1;
    }
  };

  layernorm(xn, xn, n1g, n1b);  // in-place: each token owned by one wave
  __syncthreads();

  auto run_fkan = [&](const ushort_t* cT, float acc[4][4]) {
#pragma unroll 1
    for (int ci = 0; ci < NCHK; ++ci) {
      // stage coeff chunk (128k x 128o bf16, contiguous in coefT)
      const uint4* csrc = (const uint4*)(cT + ci * KCH * DIMC);
      uint4* cdst = (uint4*)&clds[0][0];
#pragma unroll
      for (int j = 0; j < 8; ++j) cdst[tid + j * 256] = csrc[tid + j * 256];
      // generate features for 8 input channels: cos/sin(k*a), k=1..8 via recurrence
      {
        int t = tid >> 3, ip = tid & 7;
        float a = xn[t][ci * CHI + ip];
        float s1, c1;
        sincosf(a, &s1, &c1);
        int kb = ip * 16;
        feat[kb + 0][t] = c1;
        feat[kb + 1][t] = s1;
        float ck = c1, sk = s1;
#pragma unroll
        for (int g = 1; g < 8; ++g) {
          float cn = ck * c1 - sk * s1;
          float sn = sk * c1 + ck * s1;
          ck = cn; sk = sn;
          feat[kb + 2 * g][t] = ck;
          feat[kb + 2 * g + 1][t] = sk;
        }
      }
      __syncthreads();
#pragma unroll 4
      for (int k = 0; k < KCH; ++k) {
        float4 f = *(const float4*)&feat[k][tg * 4];        // 4 tokens, bcast/no-conflict
        uint2 cw = *(const uint2*)&clds[k][og * 4];         // 4 outputs, bf16
        float cv[4];
        cv[0] = __uint_as_float(cw.x << 16);
        cv[1] = __uint_as_float(cw.x & 0xffff0000u);
        cv[2] = __uint_as_float(cw.y << 16);
        cv[3] = __uint_as_float(cw.y & 0xffff0000u);
        float fv[4] = {f.x, f.y, f.z, f.w};
#pragma unroll
        for (int jt = 0; jt < 4; ++jt)
#pragma unroll
          for (int jo = 0; jo < 4; ++jo) acc[jt][jo] += fv[jt] * cv[jo];
      }
      __syncthreads();
    }
  };

  float acc[4][4];
#pragma unroll
  for (int jt = 0; jt < 4; ++jt)
#pragma unroll
    for (int jo = 0; jo < 4; ++jo) acc[jt][jo] = 0.f;
  run_fkan(coefT, acc);

  {  // bias + relu -> o1 (aliases clds; safe: run_fkan ends with barrier)
    float bia[4];
#pragma unroll
    for (int jo = 0; jo < 4; ++jo) bia[jo] = fk1b[og * 4 + jo];
#pragma unroll
    for (int jt = 0; jt < 4; ++jt) {
      float4 v;
      v.x = fmaxf(acc[jt][0] + bia[0], 0.f);
      v.y = fmaxf(acc[jt][1] + bia[1], 0.f);
      v.z = fmaxf(acc[jt][2] + bia[2], 0.f);
      v.w = fmaxf(acc[jt][3] + bia[3], 0.f);
      *(float4*)&o1[tg * 4 + jt][og * 4] = v;
    }
  }
  __syncthreads();

  layernorm(o1, xn, n2g, n2b);
  __syncthreads();

#pragma unroll
  for (int jt = 0; jt < 4; ++jt)
#pragma unroll
    for (int jo = 0; jo < 4; ++jo) acc[jt][jo] = 0.f;
  run_fkan(coefT + (size_t)KTOT * DIMC, acc);

  // bias, write out2, block-local channel-attn stats (this block IS one c4 group)
  float ls = 0.f, lm = -INFINITY;
  {
    float bia[4];
#pragma unroll
    for (int jo = 0; jo < 4; ++jo) bia[jo] = fk2b[og * 4 + jo];
#pragma unroll
    for (int jt = 0; jt < 4; ++jt) {
      float4 v;
      v.x = acc[jt][0] + bia[0];
      v.y = acc[jt][1] + bia[1];
      v.z = acc[jt][2] + bia[2];
      v.w = acc[jt][3] + bia[3];
      *(float4*)(out2 + tileBase + (size_t)(tg * 4 + jt) * DIMC + og * 4) = v;
      ls += v.x + v.y + v.z + v.w;
      lm = fmaxf(lm, fmaxf(fmaxf(v.x, v.y), fmaxf(v.z, v.w)));
    }
  }
#pragma unroll
  for (int m = 1; m < 64; m <<= 1) {
    ls += __shfl_xor(ls, m, 64);
    lm = fmaxf(lm, __shfl_xor(lm, m, 64));
  }
  float* sred = &feat[0][0];  // feat free now
  if (lane == 0) { sred[wid] = ls; sred[8 + wid] = lm; }
  __syncthreads();
  if (tid == 0) {
    float S = 0.f, M = -INFINITY;
#pragma unroll
    for (int w = 0; w < 4; ++w) { S += sred[w]; M = fmaxf(M, sred[8 + w]); }
    chanSum[bid] = S;
    chanMax[bid] = M;
  }
}

// ---------------- kernel 2: channel-attention MLP ----------------
__global__ __launch_bounds__(128) void chan_mlp_k(
    const float* __restrict__ cs, const float* __restrict__ cm,
    const float* __restrict__ w1, const float* __restrict__ w2,
    float* __restrict__ ca) {
  __shared__ float av[DIMC], mxs[DIMC], h[16];
  int b = blockIdx.x;
  int c = threadIdx.x;
  av[c] = cs[b * DIMC + c] * (1.0f / NL);
  mxs[c] = cm[b * DIMC + c];
  __syncthreads();
  if (c < 16) {
    int r = c & 7;
    const float* v = (c < 8) ? av : mxs;
    float a = 0.f;
    for (int i = 0; i < DIMC; ++i) a += v[i] * w1[r * DIMC + i];
    h[c] = fmaxf(a, 0.f);
  }
  __syncthreads();
  float z = 0.f;
#pragma unroll
  for (int r = 0; r < 8; ++r) z += (h[r] + h[8 + r]) * w2[c * 8 + r];
  ca[b * DIMC + c] = 1.0f / (1.0f + expf(-z));
}

// ---------------- kernel 3: spatial mean/max over "channels" (c4) ----------------
__global__ __launch_bounds__(128) void spatial_stats_k(
    const float* __restrict__ out2, const float* __restrict__ ca,
    float* __restrict__ sMean, float* __restrict__ sMax) {
  int b = blockIdx.x >> 5;
  int t = blockIdx.x & 31;
  int c = threadIdx.x;
  __shared__ float cas[DIMC];
  cas[c] = ca[b * DIMC + c];
  __syncthreads();
  float sum = 0.f, mx = -INFINITY;
#pragma unroll 4
  for (int c4 = 0; c4 < 128; ++c4) {
    float v = out2[(size_t)(b * NL + c4 * 32 + t) * DIMC + c] * cas[c4];
    sum += v;
    mx = fmaxf(mx, v);
  }
  sMean[b * NL + t * DIMC + c] = sum * (1.0f / DIMC);
  sMax[b * NL + t * DIMC + c] = mx;
}

// ---------------- kernel 4: 7-tap conv (row 3 of 7x7) + sigmoid + apply + residual ---
__global__ __launch_bounds__(128) void final_apply_k(
    const float* __restrict__ x, const float* __restrict__ out2,
    const float* __restrict__ ca, const float* __restrict__ sMean,
    const float* __restrict__ sMax, const float* __restrict__ convw,
    float* __restrict__ dout) {
  int b = blockIdx.x >> 5;
  int t = blockIdx.x & 31;
  int c = threadIdx.x;
  __shared__ float cas[DIMC];
  cas[c] = ca[b * DIMC + c];
  int l4 = t * DIMC + c;
  float sa = 0.f;
#pragma unroll
  for (int d = 0; d < 7; ++d) {
    int p = l4 + d - 3;
    if (p >= 0 && p < NL)
      sa += convw[21 + d] * sMean[b * NL + p] + convw[70 + d] * sMax[b * NL + p];
  }
  float sig = 1.0f / (1.0f + expf(-sa));
  __syncthreads();
#pragma unroll 2
  for (int c4 = 0; c4 < 128; ++c4) {
    size_t idx = (size_t)(b * NL + c4 * 32 + t) * DIMC + c;
    dout[idx] = x[idx] + out2[idx] * cas[c4] * sig;
  }
}

// ---------------- launch ----------------
extern "C" void kernel_launch(void* const* d_in, const int* in_sizes, int n_in,
                              void* d_out, int out_size, void* d_ws, size_t ws_size,
                              hipStream_t stream) {
  const float* x = (const float*)d_in[0];
  const float* n1g = (const float*)d_in[1];
  const float* n1b = (const float*)d_in[2];
  const float* fk1c = (const float*)d_in[3];
  const float* fk1b = (const float*)d_in[4];
  const float* n2g = (const float*)d_in[5];
  const float* n2b = (const float*)d_in[6];
  const float* fk2c = (const float*)d_in[7];
  const float* fk2b = (const float*)d_in[8];
  const float* w1 = (const float*)d_in[9];
  const float* w2 = (const float*)d_in[10];
  const float* convw = (const float*)d_in[11];

  float* ws = (float*)d_ws;
  float* out2 = ws;                                  // 8,388,608 floats (32 MB)
  ushort_t* coefT = (ushort_t*)(ws + 8388608);       // 524,288 bf16 (1 MB)
  float* chanSum = ws + 8388608 + 262144;
  float* chanMax = chanSum + 2048;
  float* ca = chanMax + 2048;
  float* sMean = ca + 2048;
  float* sMax = sMean + NB * NL;
  float* dout = (float*)d_out;

  prep_coef_k<<<2048, 256, 0, stream>>>(fk1c, fk2c, coefT);
  fkan_main_k<<<NB * (NL / TM), 256, 0, stream>>>(x, n1g, n1b, fk1b, n2g, n2b,
                                                  fk2b, coefT, out2, chanSum, chanMax);
  chan_mlp_k<<<NB, 128, 0, stream>>>(chanSum, chanMax, w1, w2, ca);
  spatial_stats_k<<<NB * 32, 128, 0, stream>>>(out2, ca, sMean, sMax);
  final_apply_k<<<NB * 32, 128, 0, stream>>>(x, out2, ca, sMean, sMax, convw, dout);
}

// Round 2
// 210.627 us; speedup vs baseline: 5.2122x; 5.2122x over previous
//
#include <hip/hip_runtime.h>
#include <math.h>

typedef unsigned short ushort_t;
typedef unsigned int uint_t;

#define DIMC 128
#define NB 16
#define NL 4096

using f32x4 = __attribute__((ext_vector_type(4))) float;
using bf16x8 = __attribute__((ext_vector_type(8))) short;

__device__ __forceinline__ ushort_t bf16rne(float f) {
  uint_t b = __float_as_uint(f);
  b += 0x7fffu + ((b >> 16) & 1u);
  return (ushort_t)(b >> 16);
}

// ---------------- kernel 0: coeffs -> B-fragment order, bf16 ----------------
// flat 16B-fragment id (per layer): G = ((ci*8 + n)*4 + s)*64 + l
// element j: col o = n*16 + (l&15); k = ci*128 + s*32 + (l>>4)*8 + j
// k -> trig=k&1, g=(k>>1)&7, i=k>>4 ; value = fk[trig][o][i][g]
__global__ __launch_bounds__(256) void prep_coef_k(const float* __restrict__ fk1,
                                                   const float* __restrict__ fk2,
                                                   ushort_t* __restrict__ coefT) {
  int idx = blockIdx.x * 256 + threadIdx.x;  // fragment id, 65536 total
  int layer = idx >> 15;
  int rem = idx & 32767;
  int ci = rem >> 11;
  int n = (rem >> 8) & 7;
  int s = (rem >> 6) & 3;
  int l = rem & 63;
  int o = n * 16 + (l & 15);
  int kbase = ci * 128 + s * 32 + (l >> 4) * 8;
  const float* src = layer ? fk2 : fk1;
  uint_t p[4];
#pragma unroll
  for (int jj = 0; jj < 4; ++jj) {
    int k0 = kbase + jj * 2;
    int t0 = k0 & 1, g0 = (k0 >> 1) & 7, i0 = k0 >> 4;
    int k1 = k0 + 1;
    int t1 = k1 & 1, g1 = (k1 >> 1) & 7, i1 = k1 >> 4;
    ushort_t a = bf16rne(src[((t0 * DIMC + o) * DIMC + i0) * 8 + g0]);
    ushort_t b = bf16rne(src[((t1 * DIMC + o) * DIMC + i1) * 8 + g1]);
    p[jj] = (uint_t)a | ((uint_t)b << 16);
  }
  uint4 w;
  w.x = p[0]; w.y = p[1]; w.z = p[2]; w.w = p[3];
  *(uint4*)&coefT[idx * 8] = w;
}

// ---------------- kernel 1: LN1 -> FKAN1(MFMA) -> ReLU -> LN2 -> FKAN2(MFMA) ----
constexpr int TM = 64;  // tokens per block (2 LCBAM channel groups)

__global__ __launch_bounds__(256, 2) void fkan_main_k(
    const float* __restrict__ x,
    const float* __restrict__ n1g, const float* __restrict__ n1b,
    const float* __restrict__ fk1b,
    const float* __restrict__ n2g, const float* __restrict__ n2b,
    const float* __restrict__ fk2b,
    const ushort_t* __restrict__ coefT,
    float* __restrict__ out2,
    float* __restrict__ chanSum, float* __restrict__ chanMax) {

  __shared__ float xln[TM][DIMC];    // 32 KB: x -> LN1 -> o1 -> LN2 -> out vals
  __shared__ ushort_t feat[8192];    // 16 KB: A fragments (1024 x 16B)
  __shared__ ushort_t cofs[16384];   // 32 KB: B fragments (2048 x 16B)

  const int tid = threadIdx.x;
  const int bid = blockIdx.x;
  const int b = bid >> 6;
  const int tg64 = bid & 63;
  const int lane = tid & 63;
  const int wid = tid >> 6;
  const size_t tileBase = ((size_t)(b * NL + tg64 * TM)) * DIMC;

  {  // load 64x128 x-tile, coalesced
    const float4* src = (const float4*)(x + tileBase);
    float4* dst = (float4*)&xln[0][0];
#pragma unroll
    for (int j = 0; j < 8; ++j) dst[tid + j * 256] = src[tid + j * 256];
  }
  __syncthreads();

  auto layernorm = [&](const float* gg, const float* bb) {
    float g0 = gg[lane], g1 = gg[lane + 64];
    float be0 = bb[lane], be1 = bb[lane + 64];
#pragma unroll
    for (int j = 0; j < 16; ++j) {
      int t = wid * 16 + j;
      float v0 = xln[t][lane], v1 = xln[t][lane + 64];
      float s = v0 + v1, q = v0 * v0 + v1 * v1;
#pragma unroll
      for (int m = 1; m < 64; m <<= 1) {
        s += __shfl_xor(s, m, 64);
        q += __shfl_xor(q, m, 64);
      }
      float mean = s * (1.0f / DIMC);
      float var = q * (1.0f / DIMC) - mean * mean;
      float rr = rsqrtf(var + 1e-5f);
      xln[t][lane] = (v0 - mean) * rr * g0 + be0;
      xln[t][lane + 64] = (v1 - mean) * rr * g1 + be1;
    }
  };

  layernorm(n1g, n1b);
  __syncthreads();

  const int mp = wid >> 1;  // wave's m-pair: m = mp*2 + mm  (token tiles)
  const int nh = wid & 1;   // wave's n-half: n = nh*4 + nn  (output tiles)

  auto run_fkan = [&](const ushort_t* cbase, f32x4(&acc)[4][2]) {
#pragma unroll 1
    for (int ci = 0; ci < 16; ++ci) {
      {  // stage B-fragment chunk (32 KB, already fragment-ordered)
        const uint4* csrc = (const uint4*)(cbase + ci * 16384);
        uint4* cdst = (uint4*)cofs;
#pragma unroll
        for (int j = 0; j < 8; ++j) cdst[tid + j * 256] = csrc[tid + j * 256];
      }
      // features: cos/sin(k*a), k=1..8 via angle-addition; write A fragments
#pragma unroll
      for (int rep = 0; rep < 2; ++rep) {
        int t = (tid >> 3) + rep * 32;
        int ip = tid & 7;
        float a = xln[t][ci * 8 + ip];
        float s1, c1;
        __sincosf(a, &s1, &c1);
        int m = t >> 4, t15 = t & 15, s = ip >> 1, hi0 = (ip & 1) * 2;
        uint_t F0 = (uint_t)((m * 4 + s) * 64 + hi0 * 16 + t15);
        uint_t p[8];
        p[0] = (uint_t)bf16rne(c1) | ((uint_t)bf16rne(s1) << 16);
        float ck = c1, sk = s1;
#pragma unroll
        for (int g = 1; g < 8; ++g) {
          float cn = ck * c1 - sk * s1;
          float sn = sk * c1 + ck * s1;
          ck = cn; sk = sn;
          p[g] = (uint_t)bf16rne(ck) | ((uint_t)bf16rne(sk) << 16);
        }
        uint4 w0, w1;
        w0.x = p[0]; w0.y = p[1]; w0.z = p[2]; w0.w = p[3];
        w1.x = p[4]; w1.y = p[5]; w1.z = p[6]; w1.w = p[7];
        *(uint4*)&feat[F0 * 8] = w0;
        *(uint4*)&feat[(F0 + 16) * 8] = w1;
      }
      __syncthreads();
      // MFMA: wave computes 2m x 4n 16x16 tiles over K=128
      bf16x8 af[2][4];
#pragma unroll
      for (int mm = 0; mm < 2; ++mm)
#pragma unroll
        for (int s = 0; s < 4; ++s)
          af[mm][s] = *(const bf16x8*)&feat[((((mp * 2 + mm) * 4 + s) * 64) + lane) * 8];
#pragma unroll
      for (int nn = 0; nn < 4; ++nn) {
        int n = nh * 4 + nn;
#pragma unroll
        for (int s = 0; s < 4; ++s) {
          bf16x8 bfr = *(const bf16x8*)&cofs[(((n * 4 + s) * 64) + lane) * 8];
#pragma unroll
          for (int mm = 0; mm < 2; ++mm)
            acc[nn][mm] = __builtin_amdgcn_mfma_f32_16x16x32_bf16(af[mm][s], bfr,
                                                                  acc[nn][mm], 0, 0, 0);
        }
      }
      __syncthreads();
    }
  };

  f32x4 acc[4][2];
#pragma unroll
  for (int nn = 0; nn < 4; ++nn)
#pragma unroll
    for (int mm = 0; mm < 2; ++mm) acc[nn][mm] = (f32x4)(0.f);
  run_fkan(coefT, acc);

  // FKAN1 epilogue: bias + ReLU -> xln  (C/D: col=lane&15, row=(lane>>4)*4+r)
#pragma unroll
  for (int nn = 0; nn < 4; ++nn) {
    int o = (nh * 4 + nn) * 16 + (lane & 15);
    float bia = fk1b[o];
#pragma unroll
    for (int mm = 0; mm < 2; ++mm) {
      int trow = (mp * 2 + mm) * 16 + (lane >> 4) * 4;
#pragma unroll
      for (int r = 0; r < 4; ++r)
        xln[trow + r][o] = fmaxf(acc[nn][mm][r] + bia, 0.f);
    }
  }
  __syncthreads();

  layernorm(n2g, n2b);
  __syncthreads();

#pragma unroll
  for (int nn = 0; nn < 4; ++nn)
#pragma unroll
    for (int mm = 0; mm < 2; ++mm) acc[nn][mm] = (f32x4)(0.f);
  run_fkan(coefT + 262144, acc);

  // FKAN2 epilogue: bias -> xln
#pragma unroll
  for (int nn = 0; nn < 4; ++nn) {
    int o = (nh * 4 + nn) * 16 + (lane & 15);
    float bia = fk2b[o];
#pragma unroll
    for (int mm = 0; mm < 2; ++mm) {
      int trow = (mp * 2 + mm) * 16 + (lane >> 4) * 4;
#pragma unroll
      for (int r = 0; r < 4; ++r)
        xln[trow + r][o] = acc[nn][mm][r] + bia;
    }
  }
  __syncthreads();

  // coalesced out2 write + block-local channel stats (2 groups of 32 tokens)
  {
    int t = tid >> 2, q = tid & 3;
    float ls = 0.f, lm = -INFINITY;
    float4* drow = (float4*)(out2 + tileBase + (size_t)t * DIMC + q * 32);
#pragma unroll
    for (int j = 0; j < 8; ++j) {
      int js = (j + t) & 7;  // stagger to balance LDS banks
      float4 v = *(const float4*)&xln[t][q * 32 + js * 4];
      drow[js] = v;
      ls += v.x + v.y + v.z + v.w;
      lm = fmaxf(lm, fmaxf(fmaxf(v.x, v.y), fmaxf(v.z, v.w)));
    }
#pragma unroll
    for (int m = 1; m < 64; m <<= 1) {
      ls += __shfl_xor(ls, m, 64);
      lm = fmaxf(lm, __shfl_xor(lm, m, 64));
    }
    float* sred = (float*)feat;
    if (lane == 0) { sred[wid] = ls; sred[8 + wid] = lm; }
    __syncthreads();
    if (tid < 2) {
      float S = sred[tid * 2] + sred[tid * 2 + 1];
      float M = fmaxf(sred[8 + tid * 2], sred[8 + tid * 2 + 1]);
      chanSum[bid * 2 + tid] = S;
      chanMax[bid * 2 + tid] = M;
    }
  }
}

// ---------------- kernel 2: channel-attention MLP ----------------
__global__ __launch_bounds__(128) void chan_mlp_k(
    const float* __restrict__ cs, const float* __restrict__ cm,
    const float* __restrict__ w1, const float* __restrict__ w2,
    float* __restrict__ ca) {
  __shared__ float av[DIMC], mxs[DIMC], h[16];
  int b = blockIdx.x;
  int c = threadIdx.x;
  av[c] = cs[b * DIMC + c] * (1.0f / NL);
  mxs[c] = cm[b * DIMC + c];
  __syncthreads();
  if (c < 16) {
    int r = c & 7;
    const float* v = (c < 8) ? av : mxs;
    float a = 0.f;
    for (int i = 0; i < DIMC; ++i) a += v[i] * w1[r * DIMC + i];
    h[c] = fmaxf(a, 0.f);
  }
  __syncthreads();
  float z = 0.f;
#pragma unroll
  for (int r = 0; r < 8; ++r) z += (h[r] + h[8 + r]) * w2[c * 8 + r];
  ca[b * DIMC + c] = 1.0f / (1.0f + expf(-z));
}

// ---------------- kernel 3: spatial mean/max over "channels" (l>>5) ----------------
__global__ __launch_bounds__(128) void spatial_stats_k(
    const float* __restrict__ out2, const float* __restrict__ ca,
    float* __restrict__ sMean, float* __restrict__ sMax) {
  int b = blockIdx.x >> 5;
  int t = blockIdx.x & 31;
  int c = threadIdx.x;
  __shared__ float cas[DIMC];
  cas[c] = ca[b * DIMC + c];
  __syncthreads();
  float sum = 0.f, mx = -INFINITY;
#pragma unroll 4
  for (int c4 = 0; c4 < 128; ++c4) {
    float v = out2[(size_t)(b * NL + c4 * 32 + t) * DIMC + c] * cas[c4];
    sum += v;
    mx = fmaxf(mx, v);
  }
  sMean[b * NL + t * DIMC + c] = sum * (1.0f / DIMC);
  sMax[b * NL + t * DIMC + c] = mx;
}

// ---------------- kernel 4: 7-tap conv + sigmoid + apply + residual ----------------
__global__ __launch_bounds__(128) void final_apply_k(
    const float* __restrict__ x, const float* __restrict__ out2,
    const float* __restrict__ ca, const float* __restrict__ sMean,
    const float* __restrict__ sMax, const float* __restrict__ convw,
    float* __restrict__ dout) {
  int b = blockIdx.x >> 5;
  int t = blockIdx.x & 31;
  int c = threadIdx.x;
  __shared__ float cas[DIMC];
  cas[c] = ca[b * DIMC + c];
  int l4 = t * DIMC + c;
  float sa = 0.f;
#pragma unroll
  for (int d = 0; d < 7; ++d) {
    int p = l4 + d - 3;
    if (p >= 0 && p < NL)
      sa += convw[21 + d] * sMean[b * NL + p] + convw[70 + d] * sMax[b * NL + p];
  }
  float sig = 1.0f / (1.0f + expf(-sa));
  __syncthreads();
#pragma unroll 2
  for (int c4 = 0; c4 < 128; ++c4) {
    size_t idx = (size_t)(b * NL + c4 * 32 + t) * DIMC + c;
    dout[idx] = x[idx] + out2[idx] * cas[c4] * sig;
  }
}

// ---------------- launch ----------------
extern "C" void kernel_launch(void* const* d_in, const int* in_sizes, int n_in,
                              void* d_out, int out_size, void* d_ws, size_t ws_size,
                              hipStream_t stream) {
  const float* x = (const float*)d_in[0];
  const float* n1g = (const float*)d_in[1];
  const float* n1b = (const float*)d_in[2];
  const float* fk1c = (const float*)d_in[3];
  const float* fk1b = (const float*)d_in[4];
  const float* n2g = (const float*)d_in[5];
  const float* n2b = (const float*)d_in[6];
  const float* fk2c = (const float*)d_in[7];
  const float* fk2b = (const float*)d_in[8];
  const float* w1 = (const float*)d_in[9];
  const float* w2 = (const float*)d_in[10];
  const float* convw = (const float*)d_in[11];

  float* ws = (float*)d_ws;
  float* out2 = ws;                             // 8,388,608 floats (32 MB)
  ushort_t* coefT = (ushort_t*)(ws + 8388608);  // 524,288 bf16 (1 MB)
  float* chanSum = ws + 8388608 + 262144;
  float* chanMax = chanSum + 2048;
  float* ca = chanMax + 2048;
  float* sMean = ca + 2048;
  float* sMax = sMean + NB * NL;
  float* dout = (float*)d_out;

  prep_coef_k<<<256, 256, 0, stream>>>(fk1c, fk2c, coefT);
  fkan_main_k<<<NB * (NL / TM), 256, 0, stream>>>(x, n1g, n1b, fk1b, n2g, n2b,
                                                  fk2b, coefT, out2, chanSum, chanMax);
  chan_mlp_k<<<NB, 128, 0, stream>>>(chanSum, chanMax, w1, w2, ca);
  spatial_stats_k<<<NB * 32, 128, 0, stream>>>(out2, ca, sMean, sMax);
  final_apply_k<<<NB * 32, 128, 0, stream>>>(x, out2, ca, sMean, sMax, convw, dout);
}

// Round 3
// 168.408 us; speedup vs baseline: 6.5189x; 1.2507x over previous
//
#include <hip/hip_runtime.h>
#include <math.h>

typedef unsigned short ushort_t;
typedef unsigned int uint_t;

#define DIMC 128
#define NB 16
#define NL 4096

using f32x4 = __attribute__((ext_vector_type(4))) float;
using bf16x8 = __attribute__((ext_vector_type(8))) short;

__device__ __forceinline__ ushort_t bf16rne(float f) {
  uint_t b = __float_as_uint(f);
  b += 0x7fffu + ((b >> 16) & 1u);
  return (ushort_t)(b >> 16);
}

// ---------------- kernel 0: coeffs -> B-fragment order, bf16 ----------------
// flat 16B-fragment id (per layer): G = ((ci*8 + n)*4 + s)*64 + l
// element j: col o = n*16 + (l&15); k = ci*128 + s*32 + (l>>4)*8 + j
// k -> trig=k&1, g=(k>>1)&7, i=k>>4 ; value = fk[trig][o][i][g]
__global__ __launch_bounds__(256) void prep_coef_k(const float* __restrict__ fk1,
                                                   const float* __restrict__ fk2,
                                                   ushort_t* __restrict__ coefT) {
  int idx = blockIdx.x * 256 + threadIdx.x;  // fragment id, 65536 total
  int layer = idx >> 15;
  int rem = idx & 32767;
  int ci = rem >> 11;
  int n = (rem >> 8) & 7;
  int s = (rem >> 6) & 3;
  int l = rem & 63;
  int o = n * 16 + (l & 15);
  int kbase = ci * 128 + s * 32 + (l >> 4) * 8;
  const float* src = layer ? fk2 : fk1;
  uint_t p[4];
#pragma unroll
  for (int jj = 0; jj < 4; ++jj) {
    int k0 = kbase + jj * 2;
    int t0 = k0 & 1, g0 = (k0 >> 1) & 7, i0 = k0 >> 4;
    int k1 = k0 + 1;
    int t1 = k1 & 1, g1 = (k1 >> 1) & 7, i1 = k1 >> 4;
    ushort_t a = bf16rne(src[((t0 * DIMC + o) * DIMC + i0) * 8 + g0]);
    ushort_t b = bf16rne(src[((t1 * DIMC + o) * DIMC + i1) * 8 + g1]);
    p[jj] = (uint_t)a | ((uint_t)b << 16);
  }
  uint4 w;
  w.x = p[0]; w.y = p[1]; w.z = p[2]; w.w = p[3];
  *(uint4*)&coefT[idx * 8] = w;
}

// ---------------- kernel 1: LN1 -> FKAN1(MFMA) -> ReLU -> LN2 -> FKAN2(MFMA) ----
constexpr int TM = 64;   // tokens per block (2 LCBAM channel groups)
constexpr int SX = 132;  // xln row stride (floats): 4*SX % 32 != 0, 16B-aligned

__global__ __launch_bounds__(256, 2) void fkan_main_k(
    const float* __restrict__ x,
    const float* __restrict__ n1g, const float* __restrict__ n1b,
    const float* __restrict__ fk1b,
    const float* __restrict__ n2g, const float* __restrict__ n2b,
    const float* __restrict__ fk2b,
    const ushort_t* __restrict__ coefT,
    float* __restrict__ out2,
    float* __restrict__ chanSum, float* __restrict__ chanMax) {

  __shared__ float xln[TM * SX];      // 33.8 KB: x -> LN1 -> o1 -> LN2
  __shared__ ushort_t feat[2][8192];  // 2 x 16 KB: A fragments, double-buffered
  __shared__ float sred[16];

  const int tid = threadIdx.x;
  const int bid = blockIdx.x;
  const int b = bid >> 6;
  const int tg64 = bid & 63;
  const int lane = tid & 63;
  const int wid = tid >> 6;
  const int mp = wid >> 1;  // wave's m-pair (token 32-group) -> also stats group
  const int nh = wid & 1;   // wave's n-half (output 64-group)
  const size_t tileBase = ((size_t)(b * NL + tg64 * TM)) * DIMC;

  {  // load 64x128 x-tile, coalesced, into strided LDS
    const float4* src = (const float4*)(x + tileBase);
#pragma unroll
    for (int j = 0; j < 8; ++j) {
      int idx = tid + j * 256;
      *(float4*)&xln[(idx >> 5) * SX + (idx & 31) * 4] = src[idx];
    }
  }
  __syncthreads();

  auto layernorm = [&](const float* gg, const float* bb) {
    float g0 = gg[lane], g1 = gg[lane + 64];
    float be0 = bb[lane], be1 = bb[lane + 64];
#pragma unroll
    for (int j = 0; j < 16; ++j) {
      int t = wid * 16 + j;  // one wave owns token t
      float v0 = xln[t * SX + lane], v1 = xln[t * SX + 64 + lane];
      float s = v0 + v1, q = v0 * v0 + v1 * v1;
#pragma unroll
      for (int m = 1; m < 64; m <<= 1) {
        s += __shfl_xor(s, m, 64);
        q += __shfl_xor(q, m, 64);
      }
      float mean = s * (1.0f / DIMC);
      float var = q * (1.0f / DIMC) - mean * mean;
      float rr = rsqrtf(var + 1e-5f);
      xln[t * SX + lane] = (v0 - mean) * rr * g0 + be0;
      xln[t * SX + 64 + lane] = (v1 - mean) * rr * g1 + be1;
    }
  };

  // features cos/sin(k*a), k=1..8 -> A fragments (XOR-swizzled slots)
  auto featgen = [&](int cj, int buf) {
#pragma unroll
    for (int rep = 0; rep < 2; ++rep) {
      int t = (tid >> 3) + rep * 32;
      int ip = tid & 7;
      float a = xln[t * SX + cj * 8 + ip];
      float s1, c1;
      __sincosf(a, &s1, &c1);
      uint4 w0, w1;
      w0.x = (uint_t)bf16rne(c1) | ((uint_t)bf16rne(s1) << 16);
      float ck = c1, sk = s1;
      {
        float cn = ck * c1 - sk * s1, sn = sk * c1 + ck * s1;
        ck = cn; sk = sn;
        w0.y = (uint_t)bf16rne(ck) | ((uint_t)bf16rne(sk) << 16);
      }
      {
        float cn = ck * c1 - sk * s1, sn = sk * c1 + ck * s1;
        ck = cn; sk = sn;
        w0.z = (uint_t)bf16rne(ck) | ((uint_t)bf16rne(sk) << 16);
      }
      {
        float cn = ck * c1 - sk * s1, sn = sk * c1 + ck * s1;
        ck = cn; sk = sn;
        w0.w = (uint_t)bf16rne(ck) | ((uint_t)bf16rne(sk) << 16);
      }
      {
        float cn = ck * c1 - sk * s1, sn = sk * c1 + ck * s1;
        ck = cn; sk = sn;
        w1.x = (uint_t)bf16rne(ck) | ((uint_t)bf16rne(sk) << 16);
      }
      {
        float cn = ck * c1 - sk * s1, sn = sk * c1 + ck * s1;
        ck = cn; sk = sn;
        w1.y = (uint_t)bf16rne(ck) | ((uint_t)bf16rne(sk) << 16);
      }
      {
        float cn = ck * c1 - sk * s1, sn = sk * c1 + ck * s1;
        ck = cn; sk = sn;
        w1.z = (uint_t)bf16rne(ck) | ((uint_t)bf16rne(sk) << 16);
      }
      {
        float cn = ck * c1 - sk * s1, sn = sk * c1 + ck * s1;
        ck = cn; sk = sn;
        w1.w = (uint_t)bf16rne(ck) | ((uint_t)bf16rne(sk) << 16);
      }
      int m = t >> 4, t15 = t & 15;
      int f = m * 4 + (ip >> 1);
      int slot0 = (((ip & 1) * 32) + t15) ^ (f & 7);  // 2-way banks: free
      *(uint4*)&feat[buf][(f * 64 + slot0) * 8] = w0;
      *(uint4*)&feat[buf][(f * 64 + slot0 + 16) * 8] = w1;
    }
  };

  layernorm(n1g, n1b);
  __syncthreads();

  f32x4 acc[4][2];

  auto run_layer = [&](const ushort_t* cbase) {
#pragma unroll
    for (int nn = 0; nn < 4; ++nn)
#pragma unroll
      for (int mm = 0; mm < 2; ++mm) acc[nn][mm] = (f32x4)(0.f);
    featgen(0, 0);
    __syncthreads();
#pragma unroll 1
    for (int ci = 0; ci < 16; ++ci) {
      // B fragments straight from global (L2-resident, lane-linear coalesced)
      bf16x8 bfr[4][4];
#pragma unroll
      for (int nn = 0; nn < 4; ++nn)
#pragma unroll
        for (int s = 0; s < 4; ++s)
          bfr[nn][s] = *(const bf16x8*)(cbase +
              (size_t)((((ci * 8 + nh * 4 + nn) * 4 + s) << 6) + lane) * 8);
      // generate NEXT chunk's features while B loads are in flight
      if (ci < 15) featgen(ci + 1, (ci + 1) & 1);
      // A fragments from LDS (swizzled lane permutation: conflict-free)
      bf16x8 af[2][4];
      const ushort_t* fb = feat[ci & 1];
#pragma unroll
      for (int mm = 0; mm < 2; ++mm)
#pragma unroll
        for (int s = 0; s < 4; ++s) {
          int f = (mp * 2 + mm) * 4 + s;
          af[mm][s] = *(const bf16x8*)&fb[((f << 6) + (lane ^ (f & 7))) * 8];
        }
      __builtin_amdgcn_s_setprio(1);
#pragma unroll
      for (int s = 0; s < 4; ++s)
#pragma unroll
        for (int nn = 0; nn < 4; ++nn)
#pragma unroll
          for (int mm = 0; mm < 2; ++mm)
            acc[nn][mm] = __builtin_amdgcn_mfma_f32_16x16x32_bf16(
                af[mm][s], bfr[nn][s], acc[nn][mm], 0, 0, 0);
      __builtin_amdgcn_s_setprio(0);
      __syncthreads();
    }
  };

  run_layer(coefT);

  // FKAN1 epilogue: bias + ReLU -> xln  (C/D: col=lane&15, row=(lane>>4)*4+r)
#pragma unroll
  for (int nn = 0; nn < 4; ++nn) {
    int o = (nh * 4 + nn) * 16 + (lane & 15);
    float bia = fk1b[o];
#pragma unroll
    for (int mm = 0; mm < 2; ++mm) {
      int trow = (mp * 2 + mm) * 16 + (lane >> 4) * 4;
#pragma unroll
      for (int r = 0; r < 4; ++r)
        xln[(trow + r) * SX + o] = fmaxf(acc[nn][mm][r] + bia, 0.f);
    }
  }
  __syncthreads();

  layernorm(n2g, n2b);
  __syncthreads();

  run_layer(coefT + 262144);

  // FKAN2 epilogue: bias -> out2 directly from accumulators + channel stats
  float ls = 0.f, lm = -INFINITY;
#pragma unroll
  for (int nn = 0; nn < 4; ++nn) {
    int o = (nh * 4 + nn) * 16 + (lane & 15);
    float bia = fk2b[o];
#pragma unroll
    for (int mm = 0; mm < 2; ++mm) {
      int trow = (mp * 2 + mm) * 16 + (lane >> 4) * 4;
#pragma unroll
      for (int r = 0; r < 4; ++r) {
        float v = acc[nn][mm][r] + bia;
        out2[tileBase + (size_t)(trow + r) * DIMC + o] = v;
        ls += v;
        lm = fmaxf(lm, v);
      }
    }
  }
#pragma unroll
  for (int m = 1; m < 64; m <<= 1) {
    ls += __shfl_xor(ls, m, 64);
    lm = fmaxf(lm, __shfl_xor(lm, m, 64));
  }
  if (lane == 0) { sred[wid] = ls; sred[8 + wid] = lm; }
  __syncthreads();
  if (tid < 2) {  // group g = token>>5 = mp -> waves {0,1} g=0, {2,3} g=1
    float S = sred[tid * 2] + sred[tid * 2 + 1];
    float M = fmaxf(sred[8 + tid * 2], sred[8 + tid * 2 + 1]);
    chanSum[bid * 2 + tid] = S;
    chanMax[bid * 2 + tid] = M;
  }
}

// ---------------- kernel 2: channel-attention MLP ----------------
__global__ __launch_bounds__(128) void chan_mlp_k(
    const float* __restrict__ cs, const float* __restrict__ cm,
    const float* __restrict__ w1, const float* __restrict__ w2,
    float* __restrict__ ca) {
  __shared__ float av[DIMC], mxs[DIMC], h[16];
  int b = blockIdx.x;
  int c = threadIdx.x;
  av[c] = cs[b * DIMC + c] * (1.0f / NL);
  mxs[c] = cm[b * DIMC + c];
  __syncthreads();
  if (c < 16) {
    int r = c & 7;
    const float* v = (c < 8) ? av : mxs;
    float a = 0.f;
    for (int i = 0; i < DIMC; ++i) a += v[i] * w1[r * DIMC + i];
    h[c] = fmaxf(a, 0.f);
  }
  __syncthreads();
  float z = 0.f;
#pragma unroll
  for (int r = 0; r < 8; ++r) z += (h[r] + h[8 + r]) * w2[c * 8 + r];
  ca[b * DIMC + c] = 1.0f / (1.0f + expf(-z));
}

// ---------------- kernel 3: spatial mean/max over "channels" (l>>5) ----------------
__global__ __launch_bounds__(128) void spatial_stats_k(
    const float* __restrict__ out2, const float* __restrict__ ca,
    float* __restrict__ sMean, float* __restrict__ sMax) {
  int b = blockIdx.x >> 5;
  int t = blockIdx.x & 31;
  int c = threadIdx.x;
  __shared__ float cas[DIMC];
  cas[c] = ca[b * DIMC + c];
  __syncthreads();
  float sum = 0.f, mx = -INFINITY;
#pragma unroll 4
  for (int c4 = 0; c4 < 128; ++c4) {
    float v = out2[(size_t)(b * NL + c4 * 32 + t) * DIMC + c] * cas[c4];
    sum += v;
    mx = fmaxf(mx, v);
  }
  sMean[b * NL + t * DIMC + c] = sum * (1.0f / DIMC);
  sMax[b * NL + t * DIMC + c] = mx;
}

// ---------------- kernel 4: 7-tap conv + sigmoid + apply + residual ----------------
__global__ __launch_bounds__(128) void final_apply_k(
    const float* __restrict__ x, const float* __restrict__ out2,
    const float* __restrict__ ca, const float* __restrict__ sMean,
    const float* __restrict__ sMax, const float* __restrict__ convw,
    float* __restrict__ dout) {
  int b = blockIdx.x >> 5;
  int t = blockIdx.x & 31;
  int c = threadIdx.x;
  __shared__ float cas[DIMC];
  cas[c] = ca[b * DIMC + c];
  int l4 = t * DIMC + c;
  float sa = 0.f;
#pragma unroll
  for (int d = 0; d < 7; ++d) {
    int p = l4 + d - 3;
    if (p >= 0 && p < NL)
      sa += convw[21 + d] * sMean[b * NL + p] + convw[70 + d] * sMax[b * NL + p];
  }
  float sig = 1.0f / (1.0f + expf(-sa));
  __syncthreads();
#pragma unroll 2
  for (int c4 = 0; c4 < 128; ++c4) {
    size_t idx = (size_t)(b * NL + c4 * 32 + t) * DIMC + c;
    dout[idx] = x[idx] + out2[idx] * cas[c4] * sig;
  }
}

// ---------------- launch ----------------
extern "C" void kernel_launch(void* const* d_in, const int* in_sizes, int n_in,
                              void* d_out, int out_size, void* d_ws, size_t ws_size,
                              hipStream_t stream) {
  const float* x = (const float*)d_in[0];
  const float* n1g = (const float*)d_in[1];
  const float* n1b = (const float*)d_in[2];
  const float* fk1c = (const float*)d_in[3];
  const float* fk1b = (const float*)d_in[4];
  const float* n2g = (const float*)d_in[5];
  const float* n2b = (const float*)d_in[6];
  const float* fk2c = (const float*)d_in[7];
  const float* fk2b = (const float*)d_in[8];
  const float* w1 = (const float*)d_in[9];
  const float* w2 = (const float*)d_in[10];
  const float* convw = (const float*)d_in[11];

  float* ws = (float*)d_ws;
  float* out2 = ws;                             // 8,388,608 floats (32 MB)
  ushort_t* coefT = (ushort_t*)(ws + 8388608);  // 524,288 bf16 (1 MB)
  float* chanSum = ws + 8388608 + 262144;
  float* chanMax = chanSum + 2048;
  float* ca = chanMax + 2048;
  float* sMean = ca + 2048;
  float* sMax = sMean + NB * NL;
  float* dout = (float*)d_out;

  prep_coef_k<<<256, 256, 0, stream>>>(fk1c, fk2c, coefT);
  fkan_main_k<<<NB * (NL / TM), 256, 0, stream>>>(x, n1g, n1b, fk1b, n2g, n2b,
                                                  fk2b, coefT, out2, chanSum, chanMax);
  chan_mlp_k<<<NB, 128, 0, stream>>>(chanSum, chanMax, w1, w2, ca);
  spatial_stats_k<<<NB * 32, 128, 0, stream>>>(out2, ca, sMean, sMax);
  final_apply_k<<<NB * 32, 128, 0, stream>>>(x, out2, ca, sMean, sMax, convw, dout);
}